// Round 1
// baseline (167.878 us; speedup 1.0000x reference)
//
#include <hip/hip_runtime.h>

#define BS 64
#define TT 2048
#define NJ 24
#define ROWF 99            // 24*4 quats + 3 pos
#define TROWS 128          // rows per block (divides TT -> tile never spans batches)
#define BLOCK 128
#define NROWS (BS * TT)    // 131072

__device__ __forceinline__ void quat2mat(float w, float x, float y, float z, float* R) {
  float s = 2.0f / (w*w + x*x + y*y + z*z);      // scale-invariant, matches reference
  float xx = s*x*x, yy = s*y*y, zz = s*z*z;
  float xy = s*x*y, xz = s*x*z, yz = s*y*z;
  float xw = s*x*w, yw = s*y*w, zw = s*z*w;
  R[0] = 1.0f - (yy+zz); R[1] = xy - zw;        R[2] = xz + yw;
  R[3] = xy + zw;        R[4] = 1.0f - (xx+zz); R[5] = yz - xw;
  R[6] = xz - yw;        R[7] = yz + xw;        R[8] = 1.0f - (xx+yy);
}

__device__ __forceinline__ void mm3(const float* A, const float* B, float* C) {
#pragma unroll
  for (int r = 0; r < 3; ++r) {
#pragma unroll
    for (int c = 0; c < 3; ++c) {
      C[3*r+c] = fmaf(A[3*r], B[c], fmaf(A[3*r+1], B[3+c], A[3*r+2]*B[6+c]));
    }
  }
}

// PHASE 0: X chain, store gtr into gtr[].  PHASE 1: Y chain, accumulate ||gtr_y-gtr_x||^2.
template<int PHASE>
__device__ __forceinline__ void fk_chain(const float* __restrict__ rowp,
                                         const float* __restrict__ tvec,
                                         float* __restrict__ gtr, float& gacc) {
  float G0[9], Ga[9], Gb[9], G9[9];
  float T0[3], Ta[3], Tb[3], T9[3];

  quat2mat(rowp[0], rowp[1], rowp[2], rowp[3], G0);
  T0[0] = rowp[96]; T0[1] = rowp[97]; T0[2] = rowp[98];
  if (PHASE == 0) { gtr[0] = T0[0]; gtr[1] = T0[1]; gtr[2] = T0[2]; }
  else { float d0 = T0[0]-gtr[0], d1 = T0[1]-gtr[1], d2 = T0[2]-gtr[2];
         gacc += d0*d0 + d1*d1 + d2*d2; }

#define STEP(c, Gp, Tp, Go, To) do { \
    float R[9]; quat2mat(rowp[4*(c)], rowp[4*(c)+1], rowp[4*(c)+2], rowp[4*(c)+3], R); \
    mm3(Gp, R, Go); \
    To[0] = fmaf(Gp[0], tvec[3*(c)], fmaf(Gp[1], tvec[3*(c)+1], fmaf(Gp[2], tvec[3*(c)+2], Tp[0]))); \
    To[1] = fmaf(Gp[3], tvec[3*(c)], fmaf(Gp[4], tvec[3*(c)+1], fmaf(Gp[5], tvec[3*(c)+2], Tp[1]))); \
    To[2] = fmaf(Gp[6], tvec[3*(c)], fmaf(Gp[7], tvec[3*(c)+1], fmaf(Gp[8], tvec[3*(c)+2], Tp[2]))); \
    if (PHASE == 0) { gtr[3*(c)] = To[0]; gtr[3*(c)+1] = To[1]; gtr[3*(c)+2] = To[2]; } \
    else { float d0 = To[0]-gtr[3*(c)], d1 = To[1]-gtr[3*(c)+1], d2 = To[2]-gtr[3*(c)+2]; \
           gacc += d0*d0 + d1*d1 + d2*d2; } \
  } while (0)

  // DFS over TOPOLOGY = [-1,0,0,0,1,2,3,4,5,6,7,8,9,9,9,12,13,14,16,17,18,19,20,21]
  STEP(1,  G0, T0, Ga, Ta); STEP(4,  Ga, Ta, Gb, Tb); STEP(7,  Gb, Tb, Ga, Ta); STEP(10, Ga, Ta, Gb, Tb);
  STEP(2,  G0, T0, Ga, Ta); STEP(5,  Ga, Ta, Gb, Tb); STEP(8,  Gb, Tb, Ga, Ta); STEP(11, Ga, Ta, Gb, Tb);
  STEP(3,  G0, T0, Ga, Ta); STEP(6,  Ga, Ta, Gb, Tb); STEP(9,  Gb, Tb, G9, T9);
  STEP(12, G9, T9, Ga, Ta); STEP(15, Ga, Ta, Gb, Tb);
  STEP(13, G9, T9, Ga, Ta); STEP(16, Ga, Ta, Gb, Tb); STEP(18, Gb, Tb, Ga, Ta); STEP(20, Ga, Ta, Gb, Tb); STEP(22, Gb, Tb, Ga, Ta);
  STEP(14, G9, T9, Ga, Ta); STEP(17, Ga, Ta, Gb, Tb); STEP(19, Gb, Tb, Ga, Ta); STEP(21, Ga, Ta, Gb, Tb); STEP(23, Gb, Tb, Ga, Ta);
#undef STEP
}

__global__ __launch_bounds__(BLOCK, 2) void motion_loss_kernel(
    const float* __restrict__ Ym, const float* __restrict__ Xm,
    const float* __restrict__ Yt, const float* __restrict__ Xt,
    float* __restrict__ out) {
  __shared__ __align__(16) float tile[TROWS * ROWF];   // 50,688 B -> 3 blocks/CU
  __shared__ float tX[NJ * 3], tY[NJ * 3];

  const int tid = threadIdx.x;
  const int blk = blockIdx.x;
  const size_t row0 = (size_t)blk * TROWS;
  const int b = blk / (TT / TROWS);                    // tile lies in one batch

  if (tid < NJ * 3) {
    tX[tid] = Xt[(size_t)b * NJ * 3 + tid];
    tY[tid] = Yt[(size_t)b * NJ * 3 + tid];
  }

  {  // stage X tile: globally contiguous, 16B-aligned (128*99*4 = 50688 = 16*3168)
    const float4* g4 = (const float4*)(Xm + row0 * ROWF);
    float4* l4 = (float4*)tile;
    for (int k = tid; k < TROWS * ROWF / 4; k += BLOCK) l4[k] = g4[k];
  }
  __syncthreads();

  // Phase 1: X forward kinematics, gtr_x kept in registers (72 VGPRs)
  float gtrX[NJ * 3];
  float gacc = 0.0f, dummy = 0.0f;
  const float* rowp = tile + tid * ROWF;   // lane stride 99 floats = 3 mod 32 banks (free)
  fk_chain<0>(rowp, tX, gtrX, dummy);
  __syncthreads();

  // Phase 2: quat-MSE + pos-MSE. Read Y from global (quat-per-thread, ~coalesced),
  // X from LDS, then overwrite LDS with Y in place (each element has one owner).
  float rot_acc = 0.0f, pos_acc = 0.0f;
  const float* __restrict__ Yg = Ym + row0 * ROWF;
#pragma unroll 4
  for (int k = 0; k < NJ; ++k) {           // 128*24 quats, 24 per thread
    int q = tid + k * BLOCK;
    int r = q / NJ;
    int j = q - r * NJ;
    int off = r * ROWF + 4 * j;
    float y0 = Yg[off], y1 = Yg[off+1], y2 = Yg[off+2], y3 = Yg[off+3];
    float x0 = tile[off], x1 = tile[off+1], x2 = tile[off+2], x3 = tile[off+3];
    float ny = fmaxf(sqrtf(y0*y0 + y1*y1 + y2*y2 + y3*y3), 1e-12f);
    float nx = fmaxf(sqrtf(x0*x0 + x1*x1 + x2*x2 + x3*x3), 1e-12f);
    float iy = 1.0f / ny, ix = 1.0f / nx;
    float d0 = y0*iy - x0*ix, d1 = y1*iy - x1*ix;
    float d2 = y2*iy - x2*ix, d3 = y3*iy - x3*ix;
    rot_acc += d0*d0 + d1*d1 + d2*d2 + d3*d3;
    tile[off] = y0; tile[off+1] = y1; tile[off+2] = y2; tile[off+3] = y3;
  }
#pragma unroll
  for (int k = 0; k < 3; ++k) {            // 128*3 pos elements, 3 per thread
    int e = tid + k * BLOCK;
    int r = e / 3;
    int c = e - r * 3;
    int off = r * ROWF + 96 + c;
    float y = Yg[off], x = tile[off];
    float d = y - x;
    pos_acc += d * d;
    tile[off] = y;
  }
  __syncthreads();

  // Phase 3: Y forward kinematics + gtr diff accumulation
  fk_chain<1>(rowp, tY, gtrX, gacc);

  const float c_rot = 1.0f / ((float)NROWS * NJ * 4);   // B1 * mean over (bs,T,24,4)
  const float c_gtr = 2.5f / ((float)NROWS * NJ * 3);   // B2 * 2.5 * mean over (bs,T,24,3)
  const float c_pos = 1.0f / ((float)NROWS * 3);        // B2 * mean over (bs,T,3)
  float contrib = c_rot * rot_acc + c_gtr * gacc + c_pos * pos_acc;
#pragma unroll
  for (int o = 32; o > 0; o >>= 1) contrib += __shfl_down(contrib, o, 64);
  if ((tid & 63) == 0) atomicAdd(out, contrib);
}

extern "C" void kernel_launch(void* const* d_in, const int* in_sizes, int n_in,
                              void* d_out, int out_size, void* d_ws, size_t ws_size,
                              hipStream_t stream) {
  const float* Ym = (const float*)d_in[0];
  const float* Xm = (const float*)d_in[1];
  const float* Yt = (const float*)d_in[2];
  const float* Xt = (const float*)d_in[3];
  float* out = (float*)d_out;
  hipMemsetAsync(out, 0, sizeof(float), stream);  // graph-capturable; d_out is poisoned pre-launch
  motion_loss_kernel<<<NROWS / TROWS, BLOCK, 0, stream>>>(Ym, Xm, Yt, Xt, out);
}